// Round 6
// baseline (991.516 us; speedup 1.0000x reference)
//
#include <hip/hip_runtime.h>
#include <hip/hip_bf16.h>

typedef unsigned short u16;
typedef unsigned int u32;

typedef short bf16v8 __attribute__((ext_vector_type(8)));
typedef float f32v4 __attribute__((ext_vector_type(4)));

// ---------------- problem constants ----------------
constexpr int BB   = 64;
constexpr int TT   = 196;
constexpr int NTOK = BB * TT;   // 12544
constexpr int DD   = 512;
constexpr int FF   = 2048;
constexpr int EE   = 8;
constexpr int NBR  = 2;
constexpr int GE   = NBR * EE;  // 16 global experts
constexpr int MT128 = 212;      // max 128-row tiles over all experts (196+16)

// meta: [0..15] u-row base per ge; [33] n128; [64..64+n128) entries (ge<<20)|tile
__device__ __forceinline__ u16 f2bf(float f) {
    union { float f; u32 u; } v; v.f = f;
    u32 r = v.u + 0x7fffu + ((v.u >> 16) & 1u);
    return (u16)(r >> 16);
}

__device__ __forceinline__ float wave_sum(float v) {
    #pragma unroll
    for (int m = 32; m > 0; m >>= 1) v += __shfl_xor(v, m, 64);
    return v;
}

// tanh-approx gelu via sigmoid: gelu(v) = v * sigmoid(1.596v + 0.0714v^3)
__device__ __forceinline__ float gelu_tanh(float v) {
    float y = 1.595769122f * v + 0.071354816f * (v * v * v);
    return v / (1.0f + __expf(-y));
}

__device__ __forceinline__ float silu(float v) {
    return v / (1.0f + __expf(-v));
}

__device__ __forceinline__ void gload16(const u16* g, u16* l) {
    typedef const __attribute__((address_space(1))) unsigned gv_t;
    typedef __attribute__((address_space(3))) unsigned lv_t;
    __builtin_amdgcn_global_load_lds((gv_t*)g, (lv_t*)l, 16, 0, 0);
}

__device__ __forceinline__ void bar() {
    asm volatile("" ::: "memory");
    __builtin_amdgcn_s_barrier();
    asm volatile("" ::: "memory");
}

#define ASM_VMCNT4 asm volatile("s_waitcnt vmcnt(4)" ::: "memory")
#define ASM_VMCNT0 asm volatile("s_waitcnt vmcnt(0)" ::: "memory")
#define ASM_LGKM0  asm volatile("s_waitcnt lgkmcnt(0)" ::: "memory")

// ---------------- merged transpose f32[R][C] -> bf16[C][R], 64x64 tiles -----
// grid: [0,4096) w1; [4096,8192) w2; [8192,8256) out_w
__global__ __launch_bounds__(256) void mtrans_kernel(
    const float* __restrict__ w1, u16* __restrict__ w1t,
    const float* __restrict__ w2, u16* __restrict__ w2t,
    const float* __restrict__ ow, u16* __restrict__ owt)
{
    __shared__ float tile[64][69];
    int id = blockIdx.x;
    const float* src; u16* dst; int R, C, rt, ct;
    if (id < 4096) {
        int e = id >> 8, rem = id & 255;
        R = DD; C = FF; rt = rem >> 5; ct = rem & 31;
        src = w1 + (size_t)e * R * C; dst = w1t + (size_t)e * R * C;
    } else if (id < 8192) {
        int e = (id - 4096) >> 8, rem = (id - 4096) & 255;
        R = FF; C = DD; rt = rem >> 3; ct = rem & 7;
        src = w2 + (size_t)e * R * C; dst = w2t + (size_t)e * R * C;
    } else {
        int rem = id - 8192;
        R = DD; C = DD; rt = rem >> 3; ct = rem & 7;
        src = ow; dst = owt;
    }
    int t = threadIdx.x;
    int tx = t & 15, ty = t >> 4;
    int r0 = rt * 64, c0 = ct * 64;
    #pragma unroll
    for (int j = 0; j < 4; ++j) {
        int row = ty + j * 16;
        float4 v = *(const float4*)&src[(size_t)(r0 + row) * C + c0 + tx * 4];
        tile[row][tx * 4 + 0] = v.x;
        tile[row][tx * 4 + 1] = v.y;
        tile[row][tx * 4 + 2] = v.z;
        tile[row][tx * 4 + 3] = v.w;
    }
    __syncthreads();
    int wc = t & 7, wr0 = t >> 3;   // 8 col-threads x 32 rows, 2 passes
    #pragma unroll
    for (int p = 0; p < 2; ++p) {
        int cc = wr0 + p * 32;
        u16 pk[8];
        #pragma unroll
        for (int i = 0; i < 8; ++i)
            pk[i] = f2bf(tile[wc * 8 + i][cc]);
        uint4 v;
        v.x = (u32)pk[0] | ((u32)pk[1] << 16);
        v.y = (u32)pk[2] | ((u32)pk[3] << 16);
        v.z = (u32)pk[4] | ((u32)pk[5] << 16);
        v.w = (u32)pk[6] | ((u32)pk[7] << 16);
        *(uint4*)&dst[(size_t)(c0 + cc) * R + r0 + wc * 8] = v;
    }
}

// ---------------- LN + gate softmax/argmax + fused routing ------------------
__global__ __launch_bounds__(256) void ln_gate_kernel(
    const float* __restrict__ x, const float* __restrict__ ln_g, const float* __restrict__ ln_b,
    const float* __restrict__ gate_w, const float* __restrict__ gate_b,
    u16* __restrict__ hA, u16* __restrict__ hB,
    int* __restrict__ cnt, int* __restrict__ list, float* __restrict__ pbuf)
{
    int wave = threadIdx.x >> 6, lane = threadIdx.x & 63;
    int tok = blockIdx.x * 4 + wave;
    const float* xr = x + (size_t)tok * DD + lane * 8;
    float4 v0 = *(const float4*)xr;
    float4 v1 = *(const float4*)(xr + 4);
    float xs[8] = {v0.x, v0.y, v0.z, v0.w, v1.x, v1.y, v1.z, v1.w};
    float s = 0.f, ss = 0.f;
    #pragma unroll
    for (int i = 0; i < 8; ++i) { s += xs[i]; ss += xs[i] * xs[i]; }
    s = wave_sum(s); ss = wave_sum(ss);
    float mu = s * (1.0f / DD);
    float var = ss * (1.0f / DD) - mu * mu;
    float rstd = rsqrtf(var + 1e-5f);

    #pragma unroll
    for (int br = 0; br < NBR; ++br) {
        u16* hb = br ? hB : hA;
        float part[8] = {0, 0, 0, 0, 0, 0, 0, 0};
        u16 hu[8];
        #pragma unroll
        for (int i = 0; i < 8; ++i) {
            int d = lane * 8 + i;
            float g = ln_g[br * DD + d], b = ln_b[br * DD + d];
            float h = (xs[i] - mu) * rstd * g + b;
            hu[i] = f2bf(h);
            const float* gw = gate_w + ((size_t)br * DD + d) * EE;
            float4 g0 = *(const float4*)gw;
            float4 g1 = *(const float4*)(gw + 4);
            part[0] += h * g0.x; part[1] += h * g0.y; part[2] += h * g0.z; part[3] += h * g0.w;
            part[4] += h * g1.x; part[5] += h * g1.y; part[6] += h * g1.z; part[7] += h * g1.w;
        }
        uint4 pk;
        pk.x = (u32)hu[0] | ((u32)hu[1] << 16);
        pk.y = (u32)hu[2] | ((u32)hu[3] << 16);
        pk.z = (u32)hu[4] | ((u32)hu[5] << 16);
        pk.w = (u32)hu[6] | ((u32)hu[7] << 16);
        *(uint4*)(hb + (size_t)tok * DD + lane * 8) = pk;

        float logit[8];
        #pragma unroll
        for (int e = 0; e < 8; ++e)
            logit[e] = wave_sum(part[e]) + gate_b[br * EE + e];
        float m = logit[0]; int bi = 0;
        #pragma unroll
        for (int e = 1; e < 8; ++e)
            if (logit[e] > m) { m = logit[e]; bi = e; }
        float sum = 0.f;
        #pragma unroll
        for (int e = 0; e < 8; ++e) sum += __expf(logit[e] - m);
        if (lane == 0) {
            int slot = atomicAdd(&cnt[br * EE + bi], 1);
            list[(size_t)(br * EE + bi) * NTOK + slot] = tok;
            pbuf[br * NTOK + tok] = 1.0f / sum;
        }
    }
}

// ---------------- tile table (128-row granular) -----------------------------
__global__ void tilestart_kernel(const int* __restrict__ cnt, int* __restrict__ meta)
{
    int lane = threadIdx.x;   // 64 threads
    if (lane < 16) {
        int pbv = 0;
        for (int k = 0; k < lane; ++k) pbv += cnt[k];
        meta[lane] = pbv;
    }
    if (lane == 16) {
        int n = 0;
        for (int k = 0; k < 16; ++k) n += (cnt[k] + 127) >> 7;
        meta[33] = n;
    }
    for (int j = lane; j < MT128; j += 64) {
        int ge = -1, start = 0, t = 0;
        #pragma unroll
        for (int k = 0; k < 16; ++k) {
            int mt = (cnt[k] + 127) >> 7;
            if (ge < 0) {
                if (j < start + mt) { ge = k; t = j - start; }
                else start += mt;
            }
        }
        if (ge >= 0) meta[64 + j] = (ge << 20) | t;
    }
}

// ---------------- A-stationary GEMM, K=512 ----------------------------------
// MODE 0: u[pos] = gelu(h[tok] @ W1[ge] + b1[ge])  A gathered, out bf16 routed
// MODE 2: dout = xres + A @ owt + out_b            A dense, out f32
// 4 waves x 32 rows = 128-row blocks. A fully in registers (af: 128 VGPR).
// B streams through LDS in 16-col chunks, double-buffered, counted vmcnt.
template<int MODE>
__global__ __launch_bounds__(256, 2) void gemm_areg(
    const u16* __restrict__ A0, const u16* __restrict__ A1, const u16* __restrict__ Bt,
    const int* __restrict__ meta, const int* __restrict__ cnt, const int* __restrict__ list,
    const float* __restrict__ bias, u16* __restrict__ uout,
    const float* __restrict__ xres, float* __restrict__ dout)
{
    constexpr int K = 512;
    constexpr int NN = (MODE == 0) ? FF : DD;
    constexpr int NCH = NN / 16;

    __shared__ __align__(16) u16 Bs[2][16 * 512];   // [chunk col][k], swizzled

    int tid = threadIdx.x, wave = tid >> 6, lane = tid & 63;
    int fr = lane & 15, fq = lane >> 4;

    int ge = 0, rb, cnt_e, pb = 0, lb = 0;
    const u16* Ab; const u16* Bte;
    if constexpr (MODE == 0) {
        int j = blockIdx.x;
        if (j >= meta[33]) return;
        int ev = meta[64 + j];
        ge = ev >> 20; rb = (ev & 0xfffff) << 7;
        cnt_e = cnt[ge]; pb = meta[ge]; lb = ge * NTOK;
        Ab = (ge >= 8) ? A1 : A0;
        Bte = Bt + (size_t)ge * FF * DD;
    } else {
        rb = blockIdx.x * 128; cnt_e = 1 << 30;
        Ab = A0; Bte = Bt;
    }

    // ---- A fragments: 2 m-strips x 16 k-steps, loaded once ----
    const u16 *ap0, *ap1;
    {
        int g0 = rb + wave * 32 + fr;
        int g1 = g0 + 16;
        if constexpr (MODE == 0) {
            int t0 = (g0 < cnt_e) ? list[lb + g0] : list[lb];
            int t1 = (g1 < cnt_e) ? list[lb + g1] : list[lb];
            ap0 = Ab + (size_t)t0 * K + fq * 8;
            ap1 = Ab + (size_t)t1 * K + fq * 8;
        } else {
            ap0 = Ab + (size_t)g0 * K + fq * 8;
            ap1 = Ab + (size_t)g1 * K + fq * 8;
        }
    }
    bf16v8 af0[16], af1[16];
    #pragma unroll
    for (int ks = 0; ks < 16; ++ks) {
        af0[ks] = *(const bf16v8*)(ap0 + ks * 32);
        af1[ks] = *(const bf16v8*)(ap1 + ks * 32);
    }

    // ---- B staging: wave stages cols wave*4..+4 of each chunk ----
    const u16* bp[4];
    #pragma unroll
    for (int i = 0; i < 4; ++i) {
        int c = wave * 4 + i;
        bp[i] = Bte + (size_t)c * K + (lane ^ (c & 7)) * 8;   // pre-swizzled source
    }
    #pragma unroll
    for (int i = 0; i < 4; ++i)
        gload16(bp[i], &Bs[0][(wave * 4 + i) * 512]);

    for (int t = 0; t < NCH; ++t) {
        int cur = t & 1;
        if (t + 1 < NCH) {
            #pragma unroll
            for (int i = 0; i < 4; ++i)
                gload16(bp[i] + (size_t)(t + 1) * 16 * K, &Bs[cur ^ 1][(wave * 4 + i) * 512]);
            ASM_VMCNT4;
        } else {
            ASM_VMCNT0;
        }
        bar();

        f32v4 a0 = {0.f, 0.f, 0.f, 0.f}, a1 = {0.f, 0.f, 0.f, 0.f};
        #pragma unroll
        for (int ks = 0; ks < 16; ++ks) {
            bf16v8 bfv = *(const bf16v8*)&Bs[cur][fr * 512 + (((ks * 4 + fq) ^ (fr & 7)) * 8)];
            a0 = __builtin_amdgcn_mfma_f32_16x16x32_bf16(af0[ks], bfv, a0, 0, 0, 0);
            a1 = __builtin_amdgcn_mfma_f32_16x16x32_bf16(af1[ks], bfv, a1, 0, 0, 0);
        }
        bar();

        // ---- chunk epilogue (D: col = fr, row = fq*4 + r) ----
        int col = t * 16 + fr;
        if constexpr (MODE == 0) {
            float bn = bias[(size_t)ge * NN + col];
            #pragma unroll
            for (int r = 0; r < 4; ++r) {
                int l0 = wave * 32 + fq * 4 + r;
                if (rb + l0 < cnt_e)
                    uout[(size_t)(pb + rb + l0) * FF + col] = f2bf(gelu_tanh(a0[r] + bn));
                int l1 = l0 + 16;
                if (rb + l1 < cnt_e)
                    uout[(size_t)(pb + rb + l1) * FF + col] = f2bf(gelu_tanh(a1[r] + bn));
            }
        } else {
            float bn = bias[col];
            #pragma unroll
            for (int r = 0; r < 4; ++r) {
                size_t o0 = (size_t)(rb + wave * 32 + fq * 4 + r) * DD + col;
                dout[o0] = xres[o0] + a0[r] + bn;
                size_t o1 = o0 + (size_t)16 * DD;
                dout[o1] = xres[o1] + a1[r] + bn;
            }
        }
    }
}

// ---------------- MODE1: moe = p * (u @ W2 + b2), K=2048 --------------------
// 4 waves x 32 rows; K split x4 (A-frags reloaded), N split x2 (acc 128 f32).
__global__ __launch_bounds__(256, 1) void gemm_m1(
    const u16* __restrict__ u, const u16* __restrict__ w2t,
    const int* __restrict__ meta, const int* __restrict__ cnt, const int* __restrict__ list,
    const float* __restrict__ pbuf, const float* __restrict__ b2,
    float* __restrict__ moe)
{
    __shared__ __align__(16) u16 Bs[2][16 * 512];
    __shared__ int rowtok[128];
    __shared__ float rowp[128];

    int j = blockIdx.x;
    if (j >= meta[33]) return;
    int ev = meta[64 + j];
    int ge = ev >> 20, rb = (ev & 0xfffff) << 7;
    int cnt_e = cnt[ge], pb = meta[ge], lb = ge * NTOK;
    int plane = ge >> 3;

    int tid = threadIdx.x, wave = tid >> 6, lane = tid & 63;
    int fr = lane & 15, fq = lane >> 4;

    if (tid < 128) {
        int g = rb + tid;
        int tk = (g < cnt_e) ? list[lb + g] : -1;
        rowtok[tid] = tk;
        rowp[tid] = (tk >= 0) ? pbuf[plane * NTOK + tk] : 0.f;
    }
    ASM_LGKM0;

    const u16* Bte = w2t + (size_t)ge * DD * FF;   // [512][2048]
    const float* b2g = b2 + (size_t)ge * DD;

    // stage chunk q (0..127): nh=q>>6, kc=(q>>4)&3, nc=q&15
    auto stage = [&](int q, int buf) {
        int nh = q >> 6, kc = (q >> 4) & 3, nc = q & 15;
        #pragma unroll
        for (int i = 0; i < 4; ++i) {
            int c = wave * 4 + i;
            int colg = nh * 256 + nc * 16 + c;
            const u16* src = Bte + (size_t)colg * FF + kc * 512 + (lane ^ (c & 7)) * 8;
            gload16(src, &Bs[buf][c * 512]);
        }
    };

    stage(0, 0);

    int arow0 = pb + rb + wave * 32 + fr;
    for (int nh = 0; nh < 2; ++nh) {
        f32v4 acc0[16], acc1[16];
        #pragma unroll
        for (int nc = 0; nc < 16; ++nc) {
            acc0[nc] = (f32v4){0.f, 0.f, 0.f, 0.f};
            acc1[nc] = (f32v4){0.f, 0.f, 0.f, 0.f};
        }
        for (int kc = 0; kc < 4; ++kc) {
            // A fragments for this K-chunk
            const u16* ap0 = u + (size_t)arow0 * FF + kc * 512 + fq * 8;
            const u16* ap1 = ap0 + (size_t)16 * FF;
            bf16v8 af0[16], af1[16];
            #pragma unroll
            for (int ks = 0; ks < 16; ++ks) {
                af0[ks] = *(const bf16v8*)(ap0 + ks * 32);
                af1[ks] = *(const bf16v8*)(ap1 + ks * 32);
            }
            int qbase = nh * 64 + kc * 16;
            #pragma unroll
            for (int nc = 0; nc < 16; ++nc) {
                int q = qbase + nc;
                if (q + 1 < 128) { stage(q + 1, (q & 1) ^ 1); ASM_VMCNT4; }
                else             { ASM_VMCNT0; }
                bar();
                #pragma unroll
                for (int ks = 0; ks < 16; ++ks) {
                    bf16v8 bfv = *(const bf16v8*)&Bs[q & 1][fr * 512 + (((ks * 4 + fq) ^ (fr & 7)) * 8)];
                    acc0[nc] = __builtin_amdgcn_mfma_f32_16x16x32_bf16(af0[ks], bfv, acc0[nc], 0, 0, 0);
                    acc1[nc] = __builtin_amdgcn_mfma_f32_16x16x32_bf16(af1[ks], bfv, acc1[nc], 0, 0, 0);
                }
                bar();
            }
        }
        // ---- store this N-half ----
        #pragma unroll
        for (int nc = 0; nc < 16; ++nc) {
            int col = nh * 256 + nc * 16 + fr;
            float bn = b2g[col];
            #pragma unroll
            for (int r = 0; r < 4; ++r) {
                int l0 = wave * 32 + fq * 4 + r;
                int tk0 = rowtok[l0];
                if (tk0 >= 0)
                    moe[((size_t)plane * NTOK + tk0) * DD + col] = (acc0[nc][r] + bn) * rowp[l0];
                int l1 = l0 + 16;
                int tk1 = rowtok[l1];
                if (tk1 >= 0)
                    moe[((size_t)plane * NTOK + tk1) * DD + col] = (acc1[nc][r] + bn) * rowp[l1];
            }
        }
    }
}

// ---------------- eo = silu(emb) @ emb_w + emb_b  [64, 1024] ----------------
__global__ __launch_bounds__(256) void eo_kernel(
    const float* __restrict__ emb, const float* __restrict__ emb_w,
    const float* __restrict__ emb_b, float* __restrict__ eo)
{
    __shared__ float se[4][DD];
    int tid = threadIdx.x;
    int b0 = blockIdx.y * 4;
    int c0 = blockIdx.x * 256 + tid;
    for (int i = tid; i < 4 * DD; i += 256) {
        int b = i >> 9, d = i & (DD - 1);
        se[b][d] = silu(emb[(size_t)(b0 + b) * DD + d]);
    }
    __syncthreads();
    float acc[4] = {0, 0, 0, 0};
    for (int k = 0; k < DD; ++k) {
        float wv = emb_w[(size_t)k * 1024 + c0];
        #pragma unroll
        for (int b = 0; b < 4; ++b) acc[b] += se[b][k] * wv;
    }
    float bb = emb_b[c0];
    #pragma unroll
    for (int b = 0; b < 4; ++b)
        eo[(size_t)(b0 + b) * 1024 + c0] = acc[b] + bb;
}

// ---------------- stylize: LN((moe0+moe1)/NB)*(1+scale)+shift -> silu -> bf16
__global__ __launch_bounds__(256) void stylize_kernel(
    const float* __restrict__ moe, const float* __restrict__ eo,
    const float* __restrict__ sn_g, const float* __restrict__ sn_b,
    u16* __restrict__ sbuf)
{
    int wave = threadIdx.x >> 6, lane = threadIdx.x & 63;
    int tok = blockIdx.x * 4 + wave;
    int b = tok / TT;
    const float* mr = moe + (size_t)tok * DD + lane * 8;
    const float* mr2 = mr + (size_t)NTOK * DD;
    float4 v0 = *(const float4*)mr;
    float4 v1 = *(const float4*)(mr + 4);
    float4 w0 = *(const float4*)mr2;
    float4 w1 = *(const float4*)(mr2 + 4);
    float os[8] = {v0.x + w0.x, v0.y + w0.y, v0.z + w0.z, v0.w + w0.w,
                   v1.x + w1.x, v1.y + w1.y, v1.z + w1.z, v1.w + w1.w};
    #pragma unroll
    for (int i = 0; i < 8; ++i) os[i] *= (1.0f / NBR);
    float s = 0.f, ss = 0.f;
    #pragma unroll
    for (int i = 0; i < 8; ++i) { s += os[i]; ss += os[i] * os[i]; }
    s = wave_sum(s); ss = wave_sum(ss);
    float mu = s * (1.0f / DD);
    float var = ss * (1.0f / DD) - mu * mu;
    float rstd = rsqrtf(var + 1e-5f);
    u16 hu[8];
    #pragma unroll
    for (int i = 0; i < 8; ++i) {
        int d = lane * 8 + i;
        float h = (os[i] - mu) * rstd * sn_g[d] + sn_b[d];
        float sc = eo[(size_t)b * 1024 + d];
        float sh = eo[(size_t)b * 1024 + DD + d];
        h = h * (1.0f + sc) + sh;
        hu[i] = f2bf(silu(h));
    }
    uint4 pk;
    pk.x = (u32)hu[0] | ((u32)hu[1] << 16);
    pk.y = (u32)hu[2] | ((u32)hu[3] << 16);
    pk.z = (u32)hu[4] | ((u32)hu[5] << 16);
    pk.w = (u32)hu[6] | ((u32)hu[7] << 16);
    *(uint4*)(sbuf + (size_t)tok * DD + lane * 8) = pk;
}

// ---------------- host ----------------
extern "C" void kernel_launch(void* const* d_in, const int* in_sizes, int n_in,
                              void* d_out, int out_size, void* d_ws, size_t ws_size,
                              hipStream_t stream)
{
    const float* x      = (const float*)d_in[0];
    const float* emb    = (const float*)d_in[1];
    const float* ln_g   = (const float*)d_in[2];
    const float* ln_b   = (const float*)d_in[3];
    const float* gate_w = (const float*)d_in[4];
    const float* gate_b = (const float*)d_in[5];
    const float* w1     = (const float*)d_in[6];
    const float* b1     = (const float*)d_in[7];
    const float* w2     = (const float*)d_in[8];
    const float* b2     = (const float*)d_in[9];
    const float* emb_w  = (const float*)d_in[10];
    const float* emb_b  = (const float*)d_in[11];
    const float* sn_g   = (const float*)d_in[12];
    const float* sn_b   = (const float*)d_in[13];
    const float* out_w  = (const float*)d_in[14];
    const float* out_b  = (const float*)d_in[15];
    (void)n_in; (void)in_sizes; (void)out_size; (void)ws_size;

    const size_t szW    = (size_t)GE * FF * DD * 2;             // 33.5 MB each
    const size_t szOwt  = (size_t)DD * DD * 2;
    const size_t szH    = (size_t)NTOK * DD * 2;                // 12.85 MB
    const size_t szEo   = (size_t)BB * 2 * DD * 4;
    const size_t szP    = (size_t)NBR * NTOK * 4;
    const size_t szCnt  = 256, szMeta = 4096;
    const size_t szList = (size_t)GE * NTOK * 4;
    const size_t szU    = ((size_t)2 * NTOK + 512) * FF * 2;    // 103.3 MB
    const size_t szM    = (size_t)2 * NTOK * DD * 4;            // 51.4 MB

    auto align256 = [](size_t v) { return (v + 255) & ~(size_t)255; };
    char* w = (char*)d_ws;
    size_t off = 0;
    auto take = [&](size_t bytes) -> void* {
        void* p = w + off;
        off = align256(off + bytes);
        return p;
    };
    u16*   w1t  = (u16*)take(szW);
    u16*   w2t  = (u16*)take(szW);
    u16*   owt  = (u16*)take(szOwt);
    u16*   hA   = (u16*)take(szH);       // reused as sbuf
    u16*   hB   = (u16*)take(szH);
    float* eo   = (float*)take(szEo);
    float* pbuf = (float*)take(szP);
    int*   cnt  = (int*)take(szCnt);
    int*   meta = (int*)take(szMeta);
    int*   list = (int*)take(szList);
    u16*   ubuf = (u16*)take(szU);
    float* moe  = (float*)take(szM);

    // 1. weight transposes -> bf16 [N][K]
    mtrans_kernel<<<8256, 256, 0, stream>>>(w1, w1t, w2, w2t, out_w, owt);

    // 2. LN + gate + fused routing
    hipMemsetAsync(cnt, 0, 64, stream);
    ln_gate_kernel<<<NTOK / 4, 256, 0, stream>>>(x, ln_g, ln_b, gate_w, gate_b,
                                                 hA, hB, cnt, list, pbuf);
    tilestart_kernel<<<1, 64, 0, stream>>>(cnt, meta);

    // 3. expert FFN (A-stationary GEMMs)
    gemm_areg<0><<<MT128, 256, 0, stream>>>(
        hA, hB, w1t, meta, cnt, list, b1, ubuf, nullptr, nullptr);
    gemm_m1<<<MT128, 256, 0, stream>>>(
        ubuf, w2t, meta, cnt, list, pbuf, b2, moe);

    // 4. stylization + output projection + residual
    eo_kernel<<<dim3(4, 16), 256, 0, stream>>>(emb, emb_w, emb_b, eo);
    stylize_kernel<<<NTOK / 4, 256, 0, stream>>>(moe, eo, sn_g, sn_b, hA);
    gemm_areg<2><<<NTOK / 128, 256, 0, stream>>>(
        hA, nullptr, owt, nullptr, nullptr, nullptr, out_b, nullptr, x, (float*)d_out);
}

// Round 7
// 613.588 us; speedup vs baseline: 1.6159x; 1.6159x over previous
//
#include <hip/hip_runtime.h>
#include <hip/hip_bf16.h>

typedef unsigned short u16;
typedef unsigned int u32;

typedef short bf16v8 __attribute__((ext_vector_type(8)));
typedef float f32v4 __attribute__((ext_vector_type(4)));

// ---------------- problem constants ----------------
constexpr int BB   = 64;
constexpr int TT   = 196;
constexpr int NTOK = BB * TT;   // 12544
constexpr int DD   = 512;
constexpr int FF   = 2048;
constexpr int EE   = 8;
constexpr int NBR  = 2;
constexpr int GE   = NBR * EE;  // 16 global experts
constexpr int MT128 = 212;      // >= max total 128-row tiles (<=210)

// meta: [0..15] u-row base (cumsum); [33] n128; [64..64+n128) (ge<<20)|tile
__device__ __forceinline__ u16 f2bf(float f) {
    union { float f; u32 u; } v; v.f = f;
    u32 r = v.u + 0x7fffu + ((v.u >> 16) & 1u);
    return (u16)(r >> 16);
}

__device__ __forceinline__ float bf2f(u32 u) {
    union { u32 u; float f; } v; v.u = u << 16; return v.f;
}

__device__ __forceinline__ float wave_sum(float v) {
    #pragma unroll
    for (int m = 32; m > 0; m >>= 1) v += __shfl_xor(v, m, 64);
    return v;
}

// tanh-approx gelu via sigmoid: gelu(v) = v * sigmoid(1.596v + 0.0714v^3)
__device__ __forceinline__ float gelu_tanh(float v) {
    float y = 1.595769122f * v + 0.071354816f * (v * v * v);
    return v / (1.0f + __expf(-y));
}

__device__ __forceinline__ float silu(float v) {
    return v / (1.0f + __expf(-v));
}

__device__ __forceinline__ void gload16(const u16* g, u16* l) {
    typedef const __attribute__((address_space(1))) unsigned gv_t;
    typedef __attribute__((address_space(3))) unsigned lv_t;
    __builtin_amdgcn_global_load_lds((gv_t*)g, (lv_t*)l, 16, 0, 0);
}

// ---------------- merged: weight transposes + eo GEMM + cnt init ------------
// grid: [0,4096) w1 64x64 tiles; [4096,8192) w2; [8192,8256) out_w; [8256,8320) eo
__global__ __launch_bounds__(256) void mtrans_eo_kernel(
    const float* __restrict__ w1, u16* __restrict__ w1t,
    const float* __restrict__ w2, u16* __restrict__ w2t,
    const float* __restrict__ ow, u16* __restrict__ owt,
    const float* __restrict__ emb, const float* __restrict__ emb_w,
    const float* __restrict__ emb_b, float* __restrict__ eo,
    int* __restrict__ cnt)
{
    __shared__ float tile[64][69];
    __shared__ float se[4][DD];
    int id = blockIdx.x;
    int t = threadIdx.x;

    if (id >= 8256) {              // ---- eo: silu(emb) @ emb_w + emb_b ----
        int id2 = id - 8256;
        int cg = id2 & 3, bg = id2 >> 2;
        int b0 = bg * 4;
        int c0 = cg * 256 + t;
        for (int i = t; i < 4 * DD; i += 256) {
            int b = i >> 9, d = i & (DD - 1);
            se[b][d] = silu(emb[(size_t)(b0 + b) * DD + d]);
        }
        __syncthreads();
        float acc[4] = {0, 0, 0, 0};
        for (int k = 0; k < DD; ++k) {
            float wv = emb_w[(size_t)k * 1024 + c0];
            #pragma unroll
            for (int b = 0; b < 4; ++b) acc[b] += se[b][k] * wv;
        }
        float bb = emb_b[c0];
        #pragma unroll
        for (int b = 0; b < 4; ++b)
            eo[(size_t)(b0 + b) * 1024 + c0] = acc[b] + bb;
        return;
    }

    if (id == 0 && t < 16) cnt[t] = 0;

    const float* src; u16* dst; int R, C, rt, ct;
    if (id < 4096) {
        int e = id >> 8, rem = id & 255;
        R = DD; C = FF; rt = rem >> 5; ct = rem & 31;
        src = w1 + (size_t)e * R * C; dst = w1t + (size_t)e * R * C;
    } else if (id < 8192) {
        int e = (id - 4096) >> 8, rem = (id - 4096) & 255;
        R = FF; C = DD; rt = rem >> 3; ct = rem & 7;
        src = w2 + (size_t)e * R * C; dst = w2t + (size_t)e * R * C;
    } else {
        int rem = id - 8192;
        R = DD; C = DD; rt = rem >> 3; ct = rem & 7;
        src = ow; dst = owt;
    }
    int tx = t & 15, ty = t >> 4;
    int r0 = rt * 64, c0 = ct * 64;
    #pragma unroll
    for (int j = 0; j < 4; ++j) {
        int row = ty + j * 16;
        float4 v = *(const float4*)&src[(size_t)(r0 + row) * C + c0 + tx * 4];
        tile[row][tx * 4 + 0] = v.x;
        tile[row][tx * 4 + 1] = v.y;
        tile[row][tx * 4 + 2] = v.z;
        tile[row][tx * 4 + 3] = v.w;
    }
    __syncthreads();
    int wc = t & 7, wr0 = t >> 3;
    #pragma unroll
    for (int p = 0; p < 2; ++p) {
        int cc = wr0 + p * 32;
        u16 pk[8];
        #pragma unroll
        for (int i = 0; i < 8; ++i)
            pk[i] = f2bf(tile[wc * 8 + i][cc]);
        uint4 v;
        v.x = (u32)pk[0] | ((u32)pk[1] << 16);
        v.y = (u32)pk[2] | ((u32)pk[3] << 16);
        v.z = (u32)pk[4] | ((u32)pk[5] << 16);
        v.w = (u32)pk[6] | ((u32)pk[7] << 16);
        *(uint4*)&dst[(size_t)(c0 + cc) * R + r0 + wc * 8] = v;
    }
}

// ---------------- LN + gate softmax/argmax + fused routing ------------------
__global__ __launch_bounds__(256) void ln_gate_kernel(
    const float* __restrict__ x, const float* __restrict__ ln_g, const float* __restrict__ ln_b,
    const float* __restrict__ gate_w, const float* __restrict__ gate_b,
    u16* __restrict__ hA, u16* __restrict__ hB,
    int* __restrict__ cnt, int* __restrict__ list, float* __restrict__ pbuf)
{
    int wave = threadIdx.x >> 6, lane = threadIdx.x & 63;
    int tok = blockIdx.x * 4 + wave;
    const float* xr = x + (size_t)tok * DD + lane * 8;
    float4 v0 = *(const float4*)xr;
    float4 v1 = *(const float4*)(xr + 4);
    float xs[8] = {v0.x, v0.y, v0.z, v0.w, v1.x, v1.y, v1.z, v1.w};
    float s = 0.f, ss = 0.f;
    #pragma unroll
    for (int i = 0; i < 8; ++i) { s += xs[i]; ss += xs[i] * xs[i]; }
    s = wave_sum(s); ss = wave_sum(ss);
    float mu = s * (1.0f / DD);
    float var = ss * (1.0f / DD) - mu * mu;
    float rstd = rsqrtf(var + 1e-5f);

    #pragma unroll
    for (int br = 0; br < NBR; ++br) {
        u16* hb = br ? hB : hA;
        float part[8] = {0, 0, 0, 0, 0, 0, 0, 0};
        u16 hu[8];
        #pragma unroll
        for (int i = 0; i < 8; ++i) {
            int d = lane * 8 + i;
            float g = ln_g[br * DD + d], b = ln_b[br * DD + d];
            float h = (xs[i] - mu) * rstd * g + b;
            hu[i] = f2bf(h);
            const float* gw = gate_w + ((size_t)br * DD + d) * EE;
            float4 g0 = *(const float4*)gw;
            float4 g1 = *(const float4*)(gw + 4);
            part[0] += h * g0.x; part[1] += h * g0.y; part[2] += h * g0.z; part[3] += h * g0.w;
            part[4] += h * g1.x; part[5] += h * g1.y; part[6] += h * g1.z; part[7] += h * g1.w;
        }
        uint4 pk;
        pk.x = (u32)hu[0] | ((u32)hu[1] << 16);
        pk.y = (u32)hu[2] | ((u32)hu[3] << 16);
        pk.z = (u32)hu[4] | ((u32)hu[5] << 16);
        pk.w = (u32)hu[6] | ((u32)hu[7] << 16);
        *(uint4*)(hb + (size_t)tok * DD + lane * 8) = pk;

        float logit[8];
        #pragma unroll
        for (int e = 0; e < 8; ++e)
            logit[e] = wave_sum(part[e]) + gate_b[br * EE + e];
        float m = logit[0]; int bi = 0;
        #pragma unroll
        for (int e = 1; e < 8; ++e)
            if (logit[e] > m) { m = logit[e]; bi = e; }
        float sum = 0.f;
        #pragma unroll
        for (int e = 0; e < 8; ++e) sum += __expf(logit[e] - m);
        if (lane == 0) {
            int slot = atomicAdd(&cnt[br * EE + bi], 1);
            list[(size_t)(br * EE + bi) * NTOK + slot] = tok;
            pbuf[br * NTOK + tok] = 1.0f / sum;
        }
    }
}

// ---------------- tile table (128-row granular) -----------------------------
__global__ void tilestart_kernel(const int* __restrict__ cnt, int* __restrict__ meta)
{
    int lane = threadIdx.x;   // 64 threads
    if (lane < 16) {
        int pbv = 0;
        for (int k = 0; k < lane; ++k) pbv += cnt[k];
        meta[lane] = pbv;
    }
    if (lane == 16) {
        int n = 0;
        for (int k = 0; k < 16; ++k) n += (cnt[k] + 127) >> 7;
        meta[33] = n;
    }
    for (int j = lane; j < MT128; j += 64) {
        int ge = -1, start = 0, tt = 0;
        #pragma unroll
        for (int k = 0; k < 16; ++k) {
            int mt = (cnt[k] + 127) >> 7;
            if (ge < 0) {
                if (j < start + mt) { ge = k; tt = j - start; }
                else start += mt;
            }
        }
        if (ge >= 0) meta[64 + j] = (ge << 20) | tt;
    }
}

// ---------------- 128x128 MFMA GEMM, BK=32, single-buffer, swizzled LDS -----
// MODE 0: u[pos] = gelu(h[tok] @ W1[ge] + b1[ge])      A gathered via list
// MODE 1: moe{plane}[tok] = p * (u[pos] @ W2[ge] + b2) A dense, bf16 out
// MODE 2: dout = xres + A @ owt + out_b                A dense, f32 out
// grid: (ntile, tileidx) — ntile fastest for A-tile L2 reuse
template<int MODE>
__global__ __launch_bounds__(256, 2) void gemm_tile(
    const u16* __restrict__ A0, const u16* __restrict__ A1,
    const u16* __restrict__ Bt,
    const int* __restrict__ meta, const int* __restrict__ cnt,
    const int* __restrict__ list, const float* __restrict__ pbuf,
    const float* __restrict__ bias,
    u16* __restrict__ uout, u16* __restrict__ moeout,
    const float* __restrict__ xres, float* __restrict__ dout)
{
    constexpr int K = (MODE == 1) ? FF : DD;
    constexpr int N = (MODE == 0) ? FF : DD;
    constexpr int NSTEP = K / 32;

    __shared__ __align__(16) u16 As[128 * 32];
    __shared__ __align__(16) u16 Bs[128 * 32];
    __shared__ int rowtok[128];
    __shared__ float rowp[128];

    int ntile = blockIdx.x;
    int ge = 0, rb = 0, cnt_e = 1 << 30, pb = 0;
    if constexpr (MODE != 2) {
        int j = blockIdx.y;
        if (j >= meta[33]) return;
        int ev = meta[64 + j];
        ge = ev >> 20;
        rb = (ev & 0xfffff) << 7;
        cnt_e = cnt[ge];
        pb = meta[ge];
    } else {
        rb = blockIdx.y * 128;
    }

    int tid = threadIdx.x, wave = tid >> 6, lane = tid & 63;
    int wm = wave >> 1, wn = wave & 1;
    int fr = lane & 15, fq = lane >> 4;
    int r0 = wave * 16 + (lane >> 2);
    int sc = (lane & 3) ^ ((lane >> 3) & 3);   // swizzled source chunk (bank fix)

    const u16* Abase;
    if constexpr (MODE == 0) Abase = (ge >= 8) ? A1 : A0;
    else                     Abase = A0;
    const u16* Bte = Bt + ((MODE == 2) ? (size_t)0 : (size_t)ge * FF * DD);

    const u16 *aSrc0, *aSrc1, *bSrc0, *bSrc1;
    if constexpr (MODE == 0) {
        int lb = ge * NTOK;
        int g0 = rb + r0, g1 = g0 + 64;
        int t0 = (g0 < cnt_e) ? list[lb + g0] : list[lb];
        int t1 = (g1 < cnt_e) ? list[lb + g1] : list[lb];
        aSrc0 = Abase + (size_t)t0 * K + sc * 8;
        aSrc1 = Abase + (size_t)t1 * K + sc * 8;
    } else {
        size_t base = (MODE == 1) ? (size_t)(pb + rb) : (size_t)rb;
        aSrc0 = Abase + (base + r0) * (size_t)K + sc * 8;
        aSrc1 = Abase + (base + r0 + 64) * (size_t)K + sc * 8;
    }
    {
        int nrow = ntile * 128 + r0;
        bSrc0 = Bte + (size_t)nrow * K + sc * 8;
        bSrc1 = Bte + (size_t)(nrow + 64) * K + sc * 8;
    }

    if constexpr (MODE == 1) {
        if (tid < 128) {
            int g = rb + tid;
            int tk = (g < cnt_e) ? list[ge * NTOK + g] : -1;
            rowtok[tid] = tk;
            rowp[tid] = (tk >= 0) ? pbuf[(ge >> 3) * NTOK + tk] : 0.f;
        }
    }

    f32v4 acc[4][4];
    #pragma unroll
    for (int mi = 0; mi < 4; ++mi)
        #pragma unroll
        for (int ni = 0; ni < 4; ++ni)
            acc[mi][ni] = (f32v4){0.f, 0.f, 0.f, 0.f};

    int ch = fq ^ ((fr >> 1) & 3);             // swizzled read chunk (bank fix)

    for (int t = 0; t < NSTEP; ++t) {
        gload16(aSrc0, &As[wave * 512]);
        gload16(aSrc1, &As[2048 + wave * 512]);
        gload16(bSrc0, &Bs[wave * 512]);
        gload16(bSrc1, &Bs[2048 + wave * 512]);
        aSrc0 += 32; aSrc1 += 32; bSrc0 += 32; bSrc1 += 32;
        __syncthreads();

        bf16v8 af[4], bfr[4];
        #pragma unroll
        for (int mi = 0; mi < 4; ++mi)
            af[mi] = *(const bf16v8*)&As[(wm * 64 + mi * 16 + fr) * 32 + ch * 8];
        #pragma unroll
        for (int ni = 0; ni < 4; ++ni)
            bfr[ni] = *(const bf16v8*)&Bs[(wn * 64 + ni * 16 + fr) * 32 + ch * 8];
        #pragma unroll
        for (int mi = 0; mi < 4; ++mi)
            #pragma unroll
            for (int ni = 0; ni < 4; ++ni)
                acc[mi][ni] = __builtin_amdgcn_mfma_f32_16x16x32_bf16(
                    af[mi], bfr[ni], acc[mi][ni], 0, 0, 0);
        __syncthreads();
    }

    // ---- epilogue (C/D frag: col = lane&15, row = fq*4 + reg) ----
    #pragma unroll
    for (int mi = 0; mi < 4; ++mi) {
        #pragma unroll
        for (int ni = 0; ni < 4; ++ni) {
            int col = ntile * 128 + wn * 64 + ni * 16 + fr;
            float bn = (MODE == 2) ? bias[col] : bias[(size_t)ge * N + col];
            #pragma unroll
            for (int r = 0; r < 4; ++r) {
                int rr = wm * 64 + mi * 16 + fq * 4 + r;
                float v = acc[mi][ni][r] + bn;
                if constexpr (MODE == 0) {
                    if (rb + rr < cnt_e)
                        uout[(size_t)(pb + rb + rr) * FF + col] = f2bf(gelu_tanh(v));
                } else if constexpr (MODE == 1) {
                    int tok = rowtok[rr];
                    if (tok >= 0)
                        moeout[((size_t)(ge >> 3) * NTOK + tok) * DD + col] =
                            f2bf(v * rowp[rr]);
                } else {
                    size_t o = (size_t)(rb + rr) * DD + col;
                    dout[o] = xres[o] + v;
                }
            }
        }
    }
}

// ---------------- stylize: LN((moe0+moe1)/2)*(1+scale)+shift -> silu -> bf16
__global__ __launch_bounds__(256) void stylize_kernel(
    const u16* __restrict__ moe, const float* __restrict__ eo,
    const float* __restrict__ sn_g, const float* __restrict__ sn_b,
    u16* __restrict__ sbuf)
{
    int wave = threadIdx.x >> 6, lane = threadIdx.x & 63;
    int tok = blockIdx.x * 4 + wave;
    int b = tok / TT;
    const u16* mr = moe + (size_t)tok * DD + lane * 8;
    const u16* mr2 = mr + (size_t)NTOK * DD;
    uint4 pa = *(const uint4*)mr;
    uint4 pb = *(const uint4*)mr2;
    float os[8];
    os[0] = (bf2f(pa.x & 0xffff) + bf2f(pb.x & 0xffff)) * 0.5f;
    os[1] = (bf2f(pa.x >> 16)    + bf2f(pb.x >> 16))    * 0.5f;
    os[2] = (bf2f(pa.y & 0xffff) + bf2f(pb.y & 0xffff)) * 0.5f;
    os[3] = (bf2f(pa.y >> 16)    + bf2f(pb.y >> 16))    * 0.5f;
    os[4] = (bf2f(pa.z & 0xffff) + bf2f(pb.z & 0xffff)) * 0.5f;
    os[5] = (bf2f(pa.z >> 16)    + bf2f(pb.z >> 16))    * 0.5f;
    os[6] = (bf2f(pa.w & 0xffff) + bf2f(pb.w & 0xffff)) * 0.5f;
    os[7] = (bf2f(pa.w >> 16)    + bf2f(pb.w >> 16))    * 0.5f;
    float s = 0.f, ss = 0.f;
    #pragma unroll
    for (int i = 0; i < 8; ++i) { s += os[i]; ss += os[i] * os[i]; }
    s = wave_sum(s); ss = wave_sum(ss);
    float mu = s * (1.0f / DD);
    float var = ss * (1.0f / DD) - mu * mu;
    float rstd = rsqrtf(var + 1e-5f);
    u16 hu[8];
    #pragma unroll
    for (int i = 0; i < 8; ++i) {
        int d = lane * 8 + i;
        float h = (os[i] - mu) * rstd * sn_g[d] + sn_b[d];
        float scv = eo[(size_t)b * 1024 + d];
        float shv = eo[(size_t)b * 1024 + DD + d];
        h = h * (1.0f + scv) + shv;
        hu[i] = f2bf(silu(h));
    }
    uint4 pk;
    pk.x = (u32)hu[0] | ((u32)hu[1] << 16);
    pk.y = (u32)hu[2] | ((u32)hu[3] << 16);
    pk.z = (u32)hu[4] | ((u32)hu[5] << 16);
    pk.w = (u32)hu[6] | ((u32)hu[7] << 16);
    *(uint4*)(sbuf + (size_t)tok * DD + lane * 8) = pk;
}

// ---------------- host ----------------
extern "C" void kernel_launch(void* const* d_in, const int* in_sizes, int n_in,
                              void* d_out, int out_size, void* d_ws, size_t ws_size,
                              hipStream_t stream)
{
    const float* x      = (const float*)d_in[0];
    const float* emb    = (const float*)d_in[1];
    const float* ln_g   = (const float*)d_in[2];
    const float* ln_b   = (const float*)d_in[3];
    const float* gate_w = (const float*)d_in[4];
    const float* gate_b = (const float*)d_in[5];
    const float* w1     = (const float*)d_in[6];
    const float* b1     = (const float*)d_in[7];
    const float* w2     = (const float*)d_in[8];
    const float* b2     = (const float*)d_in[9];
    const float* emb_w  = (const float*)d_in[10];
    const float* emb_b  = (const float*)d_in[11];
    const float* sn_g   = (const float*)d_in[12];
    const float* sn_b   = (const float*)d_in[13];
    const float* out_w  = (const float*)d_in[14];
    const float* out_b  = (const float*)d_in[15];
    (void)n_in; (void)in_sizes; (void)out_size; (void)ws_size;

    const size_t szW    = (size_t)GE * FF * DD * 2;             // 33.5 MB each
    const size_t szOwt  = (size_t)DD * DD * 2;
    const size_t szH    = (size_t)NTOK * DD * 2;                // 12.85 MB
    const size_t szEo   = (size_t)BB * 2 * DD * 4;
    const size_t szP    = (size_t)NBR * NTOK * 4;
    const size_t szCnt  = 256, szMeta = 4096;
    const size_t szList = (size_t)GE * NTOK * 4;
    const size_t szU    = ((size_t)2 * NTOK + 256) * FF * 2;    // 103 MB
    const size_t szM    = (size_t)2 * NTOK * DD * 2;            // 25.7 MB (bf16)

    auto align256 = [](size_t v) { return (v + 255) & ~(size_t)255; };
    char* w = (char*)d_ws;
    size_t off = 0;
    auto take = [&](size_t bytes) -> void* {
        void* p = w + off;
        off = align256(off + bytes);
        return p;
    };
    u16*   w1t  = (u16*)take(szW);
    u16*   w2t  = (u16*)take(szW);
    u16*   owt  = (u16*)take(szOwt);
    u16*   hA   = (u16*)take(szH);       // reused as sbuf
    u16*   hB   = (u16*)take(szH);
    float* eo   = (float*)take(szEo);
    float* pbuf = (float*)take(szP);
    int*   cnt  = (int*)take(szCnt);
    int*   meta = (int*)take(szMeta);
    int*   list = (int*)take(szList);
    u16*   ubuf = (u16*)take(szU);
    u16*   moe  = (u16*)take(szM);

    // 1. weight transposes + eo + cnt init (one dispatch)
    mtrans_eo_kernel<<<8320, 256, 0, stream>>>(w1, w1t, w2, w2t, out_w, owt,
                                               emb, emb_w, emb_b, eo, cnt);

    // 2. LN + gate + fused routing
    ln_gate_kernel<<<NTOK / 4, 256, 0, stream>>>(x, ln_g, ln_b, gate_w, gate_b,
                                                 hA, hB, cnt, list, pbuf);
    tilestart_kernel<<<1, 64, 0, stream>>>(cnt, meta);

    // 3. expert FFN (flat tile queues, ntile-fastest)
    gemm_tile<0><<<dim3(FF / 128, MT128), 256, 0, stream>>>(
        hA, hB, w1t, meta, cnt, list, nullptr, b1, ubuf, nullptr, nullptr, nullptr);
    gemm_tile<1><<<dim3(DD / 128, MT128), 256, 0, stream>>>(
        ubuf, nullptr, w2t, meta, cnt, list, pbuf, b2, nullptr, moe, nullptr, nullptr);

    // 4. stylization + output projection + residual
    stylize_kernel<<<NTOK / 4, 256, 0, stream>>>(moe, eo, sn_g, sn_b, hA);
    gemm_tile<2><<<dim3(DD / 128, NTOK / 128), 256, 0, stream>>>(
        hA, nullptr, owt, nullptr, nullptr, nullptr, nullptr, out_b,
        nullptr, nullptr, x, (float*)d_out);
}

// Round 8
// 466.177 us; speedup vs baseline: 2.1269x; 1.3162x over previous
//
#include <hip/hip_runtime.h>
#include <hip/hip_bf16.h>

typedef unsigned short u16;
typedef unsigned int u32;

typedef short bf16v8 __attribute__((ext_vector_type(8)));
typedef float f32v4 __attribute__((ext_vector_type(4)));

// ---------------- problem constants ----------------
constexpr int BB   = 64;
constexpr int TT   = 196;
constexpr int NTOK = BB * TT;   // 12544
constexpr int DD   = 512;
constexpr int FF   = 2048;
constexpr int EE   = 8;
constexpr int NBR  = 2;
constexpr int GE   = NBR * EE;  // 16 global experts
constexpr int MT128 = 212;      // >= max total 128-row tiles (<=210)

// meta: [0..15] u-row base (cumsum); [33] n128; [64..64+n128) (ge<<20)|tile
__device__ __forceinline__ u16 f2bf(float f) {
    union { float f; u32 u; } v; v.f = f;
    u32 r = v.u + 0x7fffu + ((v.u >> 16) & 1u);
    return (u16)(r >> 16);
}

__device__ __forceinline__ float bf2f(u32 u) {
    union { u32 u; float f; } v; v.u = u << 16; return v.f;
}

__device__ __forceinline__ float wave_sum(float v) {
    #pragma unroll
    for (int m = 32; m > 0; m >>= 1) v += __shfl_xor(v, m, 64);
    return v;
}

// tanh-approx gelu via sigmoid: gelu(v) = v * sigmoid(1.596v + 0.0714v^3)
__device__ __forceinline__ float gelu_tanh(float v) {
    float y = 1.595769122f * v + 0.071354816f * (v * v * v);
    return v / (1.0f + __expf(-y));
}

__device__ __forceinline__ float silu(float v) {
    return v / (1.0f + __expf(-v));
}

__device__ __forceinline__ void gload16(const u16* g, u16* l) {
    typedef const __attribute__((address_space(1))) unsigned gv_t;
    typedef __attribute__((address_space(3))) unsigned lv_t;
    __builtin_amdgcn_global_load_lds((gv_t*)g, (lv_t*)l, 16, 0, 0);
}

// ---------------- merged: weight transposes + eo GEMM + cnt init ------------
// grid: [0,4096) w1 64x64 tiles; [4096,8192) w2; [8192,8256) out_w; [8256,8320) eo
__global__ __launch_bounds__(256) void mtrans_eo_kernel(
    const float* __restrict__ w1, u16* __restrict__ w1t,
    const float* __restrict__ w2, u16* __restrict__ w2t,
    const float* __restrict__ ow, u16* __restrict__ owt,
    const float* __restrict__ emb, const float* __restrict__ emb_w,
    const float* __restrict__ emb_b, float* __restrict__ eo,
    int* __restrict__ cnt)
{
    __shared__ float tile[64][69];
    __shared__ float se[4][DD];
    int id = blockIdx.x;
    int t = threadIdx.x;

    if (id >= 8256) {              // ---- eo: silu(emb) @ emb_w + emb_b ----
        int id2 = id - 8256;
        int cg = id2 & 3, bg = id2 >> 2;
        int b0 = bg * 4;
        int c0 = cg * 256 + t;
        for (int i = t; i < 4 * DD; i += 256) {
            int b = i >> 9, d = i & (DD - 1);
            se[b][d] = silu(emb[(size_t)(b0 + b) * DD + d]);
        }
        __syncthreads();
        float acc[4] = {0, 0, 0, 0};
        for (int k = 0; k < DD; ++k) {
            float wv = emb_w[(size_t)k * 1024 + c0];
            #pragma unroll
            for (int b = 0; b < 4; ++b) acc[b] += se[b][k] * wv;
        }
        float bb = emb_b[c0];
        #pragma unroll
        for (int b = 0; b < 4; ++b)
            eo[(size_t)(b0 + b) * 1024 + c0] = acc[b] + bb;
        return;
    }

    if (id == 0 && t < 16) cnt[t] = 0;

    const float* src; u16* dst; int R, C, rt, ct;
    if (id < 4096) {
        int e = id >> 8, rem = id & 255;
        R = DD; C = FF; rt = rem >> 5; ct = rem & 31;
        src = w1 + (size_t)e * R * C; dst = w1t + (size_t)e * R * C;
    } else if (id < 8192) {
        int e = (id - 4096) >> 8, rem = (id - 4096) & 255;
        R = FF; C = DD; rt = rem >> 3; ct = rem & 7;
        src = w2 + (size_t)e * R * C; dst = w2t + (size_t)e * R * C;
    } else {
        int rem = id - 8192;
        R = DD; C = DD; rt = rem >> 3; ct = rem & 7;
        src = ow; dst = owt;
    }
    int tx = t & 15, ty = t >> 4;
    int r0 = rt * 64, c0 = ct * 64;
    #pragma unroll
    for (int j = 0; j < 4; ++j) {
        int row = ty + j * 16;
        float4 v = *(const float4*)&src[(size_t)(r0 + row) * C + c0 + tx * 4];
        tile[row][tx * 4 + 0] = v.x;
        tile[row][tx * 4 + 1] = v.y;
        tile[row][tx * 4 + 2] = v.z;
        tile[row][tx * 4 + 3] = v.w;
    }
    __syncthreads();
    int wc = t & 7, wr0 = t >> 3;
    #pragma unroll
    for (int p = 0; p < 2; ++p) {
        int cc = wr0 + p * 32;
        u16 pk[8];
        #pragma unroll
        for (int i = 0; i < 8; ++i)
            pk[i] = f2bf(tile[wc * 8 + i][cc]);
        uint4 v;
        v.x = (u32)pk[0] | ((u32)pk[1] << 16);
        v.y = (u32)pk[2] | ((u32)pk[3] << 16);
        v.z = (u32)pk[4] | ((u32)pk[5] << 16);
        v.w = (u32)pk[6] | ((u32)pk[7] << 16);
        *(uint4*)&dst[(size_t)(c0 + cc) * R + r0 + wc * 8] = v;
    }
}

// ---------------- LN + gate softmax/argmax (wave per token) -----------------
__global__ __launch_bounds__(256) void ln_gate_kernel(
    const float* __restrict__ x, const float* __restrict__ ln_g, const float* __restrict__ ln_b,
    const float* __restrict__ gate_w, const float* __restrict__ gate_b,
    u16* __restrict__ hA, u16* __restrict__ hB,
    int* __restrict__ idxb, float* __restrict__ pbuf)
{
    int wave = threadIdx.x >> 6, lane = threadIdx.x & 63;
    int tok = blockIdx.x * 4 + wave;
    const float* xr = x + (size_t)tok * DD + lane * 8;
    float4 v0 = *(const float4*)xr;
    float4 v1 = *(const float4*)(xr + 4);
    float xs[8] = {v0.x, v0.y, v0.z, v0.w, v1.x, v1.y, v1.z, v1.w};
    float s = 0.f, ss = 0.f;
    #pragma unroll
    for (int i = 0; i < 8; ++i) { s += xs[i]; ss += xs[i] * xs[i]; }
    s = wave_sum(s); ss = wave_sum(ss);
    float mu = s * (1.0f / DD);
    float var = ss * (1.0f / DD) - mu * mu;
    float rstd = rsqrtf(var + 1e-5f);

    #pragma unroll
    for (int br = 0; br < NBR; ++br) {
        u16* hb = br ? hB : hA;
        float part[8] = {0, 0, 0, 0, 0, 0, 0, 0};
        u16 hu[8];
        #pragma unroll
        for (int i = 0; i < 8; ++i) {
            int d = lane * 8 + i;
            float g = ln_g[br * DD + d], b = ln_b[br * DD + d];
            float h = (xs[i] - mu) * rstd * g + b;
            hu[i] = f2bf(h);
            const float* gw = gate_w + ((size_t)br * DD + d) * EE;
            float4 g0 = *(const float4*)gw;
            float4 g1 = *(const float4*)(gw + 4);
            part[0] += h * g0.x; part[1] += h * g0.y; part[2] += h * g0.z; part[3] += h * g0.w;
            part[4] += h * g1.x; part[5] += h * g1.y; part[6] += h * g1.z; part[7] += h * g1.w;
        }
        uint4 pk;
        pk.x = (u32)hu[0] | ((u32)hu[1] << 16);
        pk.y = (u32)hu[2] | ((u32)hu[3] << 16);
        pk.z = (u32)hu[4] | ((u32)hu[5] << 16);
        pk.w = (u32)hu[6] | ((u32)hu[7] << 16);
        *(uint4*)(hb + (size_t)tok * DD + lane * 8) = pk;

        float logit[8];
        #pragma unroll
        for (int e = 0; e < 8; ++e)
            logit[e] = wave_sum(part[e]) + gate_b[br * EE + e];
        float m = logit[0]; int bi = 0;
        #pragma unroll
        for (int e = 1; e < 8; ++e)
            if (logit[e] > m) { m = logit[e]; bi = e; }
        float sum = 0.f;
        #pragma unroll
        for (int e = 0; e < 8; ++e) sum += __expf(logit[e] - m);
        if (lane == 0) {
            idxb[br * NTOK + tok] = bi;
            pbuf[br * NTOK + tok] = 1.0f / sum;
        }
    }
}

// ---------------- routing (dense 64-lane vector atomics) --------------------
__global__ void route_kernel(const int* __restrict__ idxb, int* __restrict__ cnt,
                             int* __restrict__ list)
{
    int t = blockIdx.x * 256 + threadIdx.x;
    if (t >= NTOK) return;
    #pragma unroll
    for (int br = 0; br < NBR; ++br) {
        int e = idxb[br * NTOK + t];
        int slot = atomicAdd(&cnt[br * EE + e], 1);
        list[(size_t)(br * EE + e) * NTOK + slot] = t;
    }
}

// ---------------- tile table (128-row granular) -----------------------------
__global__ void tilestart_kernel(const int* __restrict__ cnt, int* __restrict__ meta)
{
    int lane = threadIdx.x;   // 64 threads
    if (lane < 16) {
        int pbv = 0;
        for (int k = 0; k < lane; ++k) pbv += cnt[k];
        meta[lane] = pbv;
    }
    if (lane == 16) {
        int n = 0;
        for (int k = 0; k < 16; ++k) n += (cnt[k] + 127) >> 7;
        meta[33] = n;
    }
    for (int j = lane; j < MT128; j += 64) {
        int ge = -1, start = 0, tt = 0;
        #pragma unroll
        for (int k = 0; k < 16; ++k) {
            int mt = (cnt[k] + 127) >> 7;
            if (ge < 0) {
                if (j < start + mt) { ge = k; tt = j - start; }
                else start += mt;
            }
        }
        if (ge >= 0) meta[64 + j] = (ge << 20) | tt;
    }
}

// ---------------- 128x128 MFMA GEMM, BK=32, single-buffer, swizzled LDS -----
// MODE 0: u[pos] = gelu(h[tok] @ W1[ge] + b1[ge])      A gathered via list
// MODE 1: moe{plane}[tok] = p * (u[pos] @ W2[ge] + b2) A dense, bf16 out
// MODE 2: dout = xres + A @ owt + out_b                A dense, f32 out
// grid: (ntile, tileidx) — ntile fastest for A-tile L2 reuse
template<int MODE>
__global__ __launch_bounds__(256, 2) void gemm_tile(
    const u16* __restrict__ A0, const u16* __restrict__ A1,
    const u16* __restrict__ Bt,
    const int* __restrict__ meta, const int* __restrict__ cnt,
    const int* __restrict__ list, const float* __restrict__ pbuf,
    const float* __restrict__ bias,
    u16* __restrict__ uout, u16* __restrict__ moeout,
    const float* __restrict__ xres, float* __restrict__ dout)
{
    constexpr int K = (MODE == 1) ? FF : DD;
    constexpr int N = (MODE == 0) ? FF : DD;
    constexpr int NSTEP = K / 32;

    __shared__ __align__(16) u16 As[128 * 32];
    __shared__ __align__(16) u16 Bs[128 * 32];
    __shared__ int rowtok[128];
    __shared__ float rowp[128];

    int ntile = blockIdx.x;
    int ge = 0, rb = 0, cnt_e = 1 << 30, pb = 0;
    if constexpr (MODE != 2) {
        int j = blockIdx.y;
        if (j >= meta[33]) return;
        int ev = meta[64 + j];
        ge = ev >> 20;
        rb = (ev & 0xfffff) << 7;
        cnt_e = cnt[ge];
        pb = meta[ge];
    } else {
        rb = blockIdx.y * 128;
    }

    int tid = threadIdx.x, wave = tid >> 6, lane = tid & 63;
    int wm = wave >> 1, wn = wave & 1;
    int fr = lane & 15, fq = lane >> 4;
    int r0 = wave * 16 + (lane >> 2);
    int sc = (lane & 3) ^ ((lane >> 3) & 3);   // swizzled source chunk (bank fix)

    const u16* Abase;
    if constexpr (MODE == 0) Abase = (ge >= 8) ? A1 : A0;
    else                     Abase = A0;
    const u16* Bte = Bt + ((MODE == 2) ? (size_t)0 : (size_t)ge * FF * DD);

    const u16 *aSrc0, *aSrc1, *bSrc0, *bSrc1;
    if constexpr (MODE == 0) {
        int lb = ge * NTOK;
        int g0 = rb + r0, g1 = g0 + 64;
        int t0 = (g0 < cnt_e) ? list[lb + g0] : list[lb];
        int t1 = (g1 < cnt_e) ? list[lb + g1] : list[lb];
        aSrc0 = Abase + (size_t)t0 * K + sc * 8;
        aSrc1 = Abase + (size_t)t1 * K + sc * 8;
    } else {
        size_t base = (MODE == 1) ? (size_t)(pb + rb) : (size_t)rb;
        aSrc0 = Abase + (base + r0) * (size_t)K + sc * 8;
        aSrc1 = Abase + (base + r0 + 64) * (size_t)K + sc * 8;
    }
    {
        int nrow = ntile * 128 + r0;
        bSrc0 = Bte + (size_t)nrow * K + sc * 8;
        bSrc1 = Bte + (size_t)(nrow + 64) * K + sc * 8;
    }

    if constexpr (MODE == 1) {
        if (tid < 128) {
            int g = rb + tid;
            int tk = (g < cnt_e) ? list[ge * NTOK + g] : -1;
            rowtok[tid] = tk;
            rowp[tid] = (tk >= 0) ? pbuf[(ge >> 3) * NTOK + tk] : 0.f;
        }
    }

    f32v4 acc[4][4];
    #pragma unroll
    for (int mi = 0; mi < 4; ++mi)
        #pragma unroll
        for (int ni = 0; ni < 4; ++ni)
            acc[mi][ni] = (f32v4){0.f, 0.f, 0.f, 0.f};

    int ch = fq ^ ((fr >> 1) & 3);             // swizzled read chunk (bank fix)

    for (int t = 0; t < NSTEP; ++t) {
        gload16(aSrc0, &As[wave * 512]);
        gload16(aSrc1, &As[2048 + wave * 512]);
        gload16(bSrc0, &Bs[wave * 512]);
        gload16(bSrc1, &Bs[2048 + wave * 512]);
        aSrc0 += 32; aSrc1 += 32; bSrc0 += 32; bSrc1 += 32;
        __syncthreads();

        bf16v8 af[4], bfr[4];
        #pragma unroll
        for (int mi = 0; mi < 4; ++mi)
            af[mi] = *(const bf16v8*)&As[(wm * 64 + mi * 16 + fr) * 32 + ch * 8];
        #pragma unroll
        for (int ni = 0; ni < 4; ++ni)
            bfr[ni] = *(const bf16v8*)&Bs[(wn * 64 + ni * 16 + fr) * 32 + ch * 8];
        #pragma unroll
        for (int mi = 0; mi < 4; ++mi)
            #pragma unroll
            for (int ni = 0; ni < 4; ++ni)
                acc[mi][ni] = __builtin_amdgcn_mfma_f32_16x16x32_bf16(
                    af[mi], bfr[ni], acc[mi][ni], 0, 0, 0);
        __syncthreads();
    }

    // ---- epilogue (C/D frag: col = lane&15, row = fq*4 + reg) ----
    #pragma unroll
    for (int mi = 0; mi < 4; ++mi) {
        #pragma unroll
        for (int ni = 0; ni < 4; ++ni) {
            int col = ntile * 128 + wn * 64 + ni * 16 + fr;
            float bn = (MODE == 2) ? bias[col] : bias[(size_t)ge * N + col];
            #pragma unroll
            for (int r = 0; r < 4; ++r) {
                int rr = wm * 64 + mi * 16 + fq * 4 + r;
                float v = acc[mi][ni][r] + bn;
                if constexpr (MODE == 0) {
                    if (rb + rr < cnt_e)
                        uout[(size_t)(pb + rb + rr) * FF + col] = f2bf(gelu_tanh(v));
                } else if constexpr (MODE == 1) {
                    int tok = rowtok[rr];
                    if (tok >= 0)
                        moeout[((size_t)(ge >> 3) * NTOK + tok) * DD + col] =
                            f2bf(v * rowp[rr]);
                } else {
                    size_t o = (size_t)(rb + rr) * DD + col;
                    dout[o] = xres[o] + v;
                }
            }
        }
    }
}

// ---------------- stylize: LN((moe0+moe1)/2)*(1+scale)+shift -> silu -> bf16
__global__ __launch_bounds__(256) void stylize_kernel(
    const u16* __restrict__ moe, const float* __restrict__ eo,
    const float* __restrict__ sn_g, const float* __restrict__ sn_b,
    u16* __restrict__ sbuf)
{
    int wave = threadIdx.x >> 6, lane = threadIdx.x & 63;
    int tok = blockIdx.x * 4 + wave;
    int b = tok / TT;
    const u16* mr = moe + (size_t)tok * DD + lane * 8;
    const u16* mr2 = mr + (size_t)NTOK * DD;
    uint4 pa = *(const uint4*)mr;
    uint4 pb = *(const uint4*)mr2;
    float os[8];
    os[0] = (bf2f(pa.x & 0xffff) + bf2f(pb.x & 0xffff)) * 0.5f;
    os[1] = (bf2f(pa.x >> 16)    + bf2f(pb.x >> 16))    * 0.5f;
    os[2] = (bf2f(pa.y & 0xffff) + bf2f(pb.y & 0xffff)) * 0.5f;
    os[3] = (bf2f(pa.y >> 16)    + bf2f(pb.y >> 16))    * 0.5f;
    os[4] = (bf2f(pa.z & 0xffff) + bf2f(pb.z & 0xffff)) * 0.5f;
    os[5] = (bf2f(pa.z >> 16)    + bf2f(pb.z >> 16))    * 0.5f;
    os[6] = (bf2f(pa.w & 0xffff) + bf2f(pb.w & 0xffff)) * 0.5f;
    os[7] = (bf2f(pa.w >> 16)    + bf2f(pb.w >> 16))    * 0.5f;
    float s = 0.f, ss = 0.f;
    #pragma unroll
    for (int i = 0; i < 8; ++i) { s += os[i]; ss += os[i] * os[i]; }
    s = wave_sum(s); ss = wave_sum(ss);
    float mu = s * (1.0f / DD);
    float var = ss * (1.0f / DD) - mu * mu;
    float rstd = rsqrtf(var + 1e-5f);
    u16 hu[8];
    #pragma unroll
    for (int i = 0; i < 8; ++i) {
        int d = lane * 8 + i;
        float h = (os[i] - mu) * rstd * sn_g[d] + sn_b[d];
        float scv = eo[(size_t)b * 1024 + d];
        float shv = eo[(size_t)b * 1024 + DD + d];
        h = h * (1.0f + scv) + shv;
        hu[i] = f2bf(silu(h));
    }
    uint4 pk;
    pk.x = (u32)hu[0] | ((u32)hu[1] << 16);
    pk.y = (u32)hu[2] | ((u32)hu[3] << 16);
    pk.z = (u32)hu[4] | ((u32)hu[5] << 16);
    pk.w = (u32)hu[6] | ((u32)hu[7] << 16);
    *(uint4*)(sbuf + (size_t)tok * DD + lane * 8) = pk;
}

// ---------------- host ----------------
extern "C" void kernel_launch(void* const* d_in, const int* in_sizes, int n_in,
                              void* d_out, int out_size, void* d_ws, size_t ws_size,
                              hipStream_t stream)
{
    const float* x      = (const float*)d_in[0];
    const float* emb    = (const float*)d_in[1];
    const float* ln_g   = (const float*)d_in[2];
    const float* ln_b   = (const float*)d_in[3];
    const float* gate_w = (const float*)d_in[4];
    const float* gate_b = (const float*)d_in[5];
    const float* w1     = (const float*)d_in[6];
    const float* b1     = (const float*)d_in[7];
    const float* w2     = (const float*)d_in[8];
    const float* b2     = (const float*)d_in[9];
    const float* emb_w  = (const float*)d_in[10];
    const float* emb_b  = (const float*)d_in[11];
    const float* sn_g   = (const float*)d_in[12];
    const float* sn_b   = (const float*)d_in[13];
    const float* out_w  = (const float*)d_in[14];
    const float* out_b  = (const float*)d_in[15];
    (void)n_in; (void)in_sizes; (void)out_size; (void)ws_size;

    const size_t szW    = (size_t)GE * FF * DD * 2;             // 33.5 MB each
    const size_t szOwt  = (size_t)DD * DD * 2;
    const size_t szH    = (size_t)NTOK * DD * 2;                // 12.85 MB
    const size_t szEo   = (size_t)BB * 2 * DD * 4;
    const size_t szP    = (size_t)NBR * NTOK * 4;
    const size_t szCnt  = 256, szMeta = 4096;
    const size_t szList = (size_t)GE * NTOK * 4;
    const size_t szU    = ((size_t)2 * NTOK + 256) * FF * 2;    // 103 MB
    const size_t szM    = (size_t)2 * NTOK * DD * 2;            // 25.7 MB (bf16)

    auto align256 = [](size_t v) { return (v + 255) & ~(size_t)255; };
    char* w = (char*)d_ws;
    size_t off = 0;
    auto take = [&](size_t bytes) -> void* {
        void* p = w + off;
        off = align256(off + bytes);
        return p;
    };
    u16*   w1t  = (u16*)take(szW);
    u16*   w2t  = (u16*)take(szW);
    u16*   owt  = (u16*)take(szOwt);
    u16*   hA   = (u16*)take(szH);       // reused as sbuf
    u16*   hB   = (u16*)take(szH);
    float* eo   = (float*)take(szEo);
    float* pbuf = (float*)take(szP);
    int*   idxb = (int*)take(szP);
    int*   cnt  = (int*)take(szCnt);
    int*   meta = (int*)take(szMeta);
    int*   list = (int*)take(szList);
    u16*   ubuf = (u16*)take(szU);
    u16*   moe  = (u16*)take(szM);

    // 1. weight transposes + eo + cnt init (one dispatch)
    mtrans_eo_kernel<<<8320, 256, 0, stream>>>(w1, w1t, w2, w2t, out_w, owt,
                                               emb, emb_w, emb_b, eo, cnt);

    // 2. LN + gate
    ln_gate_kernel<<<NTOK / 4, 256, 0, stream>>>(x, ln_g, ln_b, gate_w, gate_b,
                                                 hA, hB, idxb, pbuf);

    // 3. routing (dense vector atomics) + tile table
    route_kernel<<<(NTOK + 255) / 256, 256, 0, stream>>>(idxb, cnt, list);
    tilestart_kernel<<<1, 64, 0, stream>>>(cnt, meta);

    // 4. expert FFN (flat tile queues, ntile-fastest)
    gemm_tile<0><<<dim3(FF / 128, MT128), 256, 0, stream>>>(
        hA, hB, w1t, meta, cnt, list, nullptr, b1, ubuf, nullptr, nullptr, nullptr);
    gemm_tile<1><<<dim3(DD / 128, MT128), 256, 0, stream>>>(
        ubuf, nullptr, w2t, meta, cnt, list, pbuf, b2, nullptr, moe, nullptr, nullptr);

    // 5. stylization + output projection + residual
    stylize_kernel<<<NTOK / 4, 256, 0, stream>>>(moe, eo, sn_g, sn_b, hA);
    gemm_tile<2><<<dim3(DD / 128, NTOK / 128), 256, 0, stream>>>(
        hA, nullptr, owt, nullptr, nullptr, nullptr, nullptr, out_b,
        nullptr, nullptr, x, (float*)d_out);
}

// Round 9
// 370.864 us; speedup vs baseline: 2.6735x; 1.2570x over previous
//
#include <hip/hip_runtime.h>
#include <hip/hip_bf16.h>

typedef unsigned short u16;
typedef unsigned int u32;

typedef short bf16v8 __attribute__((ext_vector_type(8)));
typedef float f32v4 __attribute__((ext_vector_type(4)));

// ---------------- problem constants ----------------
constexpr int BB   = 64;
constexpr int TT   = 196;
constexpr int NTOK = BB * TT;   // 12544
constexpr int DD   = 512;
constexpr int FF   = 2048;
constexpr int EE   = 8;
constexpr int NBR  = 2;
constexpr int GE   = NBR * EE;  // 16 global experts
constexpr int MT128 = 212;      // >= max total 128-row tiles (<=210)

// meta: [0..15] u-row base (cumsum); [33] n128; [64..64+n128) (ge<<20)|tile
__device__ __forceinline__ u16 f2bf(float f) {
    union { float f; u32 u; } v; v.f = f;
    u32 r = v.u + 0x7fffu + ((v.u >> 16) & 1u);
    return (u16)(r >> 16);
}

__device__ __forceinline__ float bf2f(u32 u) {
    union { u32 u; float f; } v; v.u = u << 16; return v.f;
}

__device__ __forceinline__ float wave_sum(float v) {
    #pragma unroll
    for (int m = 32; m > 0; m >>= 1) v += __shfl_xor(v, m, 64);
    return v;
}

// tanh-approx gelu via sigmoid: gelu(v) = v * sigmoid(1.596v + 0.0714v^3)
__device__ __forceinline__ float gelu_tanh(float v) {
    float y = 1.595769122f * v + 0.071354816f * (v * v * v);
    return v / (1.0f + __expf(-y));
}

__device__ __forceinline__ float silu(float v) {
    return v / (1.0f + __expf(-v));
}

__device__ __forceinline__ void gload16(const u16* g, u16* l) {
    typedef const __attribute__((address_space(1))) unsigned gv_t;
    typedef __attribute__((address_space(3))) unsigned lv_t;
    __builtin_amdgcn_global_load_lds((gv_t*)g, (lv_t*)l, 16, 0, 0);
}

__device__ __forceinline__ void bar() {
    asm volatile("" ::: "memory");
    __builtin_amdgcn_s_barrier();
    asm volatile("" ::: "memory");
}

#define ASM_VMCNT4 asm volatile("s_waitcnt vmcnt(4)" ::: "memory")
#define ASM_VMCNT0 asm volatile("s_waitcnt vmcnt(0)" ::: "memory")
#define ASM_LGKM0  asm volatile("s_waitcnt lgkmcnt(0)" ::: "memory")

// ---------------- merged: weight transposes + eo GEMM + cnt init ------------
// grid: [0,4096) w1 64x64 tiles; [4096,8192) w2; [8192,8256) out_w; [8256,8320) eo
__global__ __launch_bounds__(256) void mtrans_eo_kernel(
    const float* __restrict__ w1, u16* __restrict__ w1t,
    const float* __restrict__ w2, u16* __restrict__ w2t,
    const float* __restrict__ ow, u16* __restrict__ owt,
    const float* __restrict__ emb, const float* __restrict__ emb_w,
    const float* __restrict__ emb_b, float* __restrict__ eo,
    int* __restrict__ cnt)
{
    __shared__ float tile[64][69];
    __shared__ float se[4][DD];
    int id = blockIdx.x;
    int t = threadIdx.x;

    if (id >= 8256) {              // ---- eo: silu(emb) @ emb_w + emb_b ----
        int id2 = id - 8256;
        int cg = id2 & 3, bg = id2 >> 2;
        int b0 = bg * 4;
        int c0 = cg * 256 + t;
        for (int i = t; i < 4 * DD; i += 256) {
            int b = i >> 9, d = i & (DD - 1);
            se[b][d] = silu(emb[(size_t)(b0 + b) * DD + d]);
        }
        __syncthreads();
        float acc[4] = {0, 0, 0, 0};
        for (int k = 0; k < DD; ++k) {
            float wv = emb_w[(size_t)k * 1024 + c0];
            #pragma unroll
            for (int b = 0; b < 4; ++b) acc[b] += se[b][k] * wv;
        }
        float bb = emb_b[c0];
        #pragma unroll
        for (int b = 0; b < 4; ++b)
            eo[(size_t)(b0 + b) * 1024 + c0] = acc[b] + bb;
        return;
    }

    if (id == 0 && t < 16) cnt[t] = 0;

    const float* src; u16* dst; int R, C, rt, ct;
    if (id < 4096) {
        int e = id >> 8, rem = id & 255;
        R = DD; C = FF; rt = rem >> 5; ct = rem & 31;
        src = w1 + (size_t)e * R * C; dst = w1t + (size_t)e * R * C;
    } else if (id < 8192) {
        int e = (id - 4096) >> 8, rem = (id - 4096) & 255;
        R = FF; C = DD; rt = rem >> 3; ct = rem & 7;
        src = w2 + (size_t)e * R * C; dst = w2t + (size_t)e * R * C;
    } else {
        int rem = id - 8192;
        R = DD; C = DD; rt = rem >> 3; ct = rem & 7;
        src = ow; dst = owt;
    }
    int tx = t & 15, ty = t >> 4;
    int r0 = rt * 64, c0 = ct * 64;
    #pragma unroll
    for (int j = 0; j < 4; ++j) {
        int row = ty + j * 16;
        float4 v = *(const float4*)&src[(size_t)(r0 + row) * C + c0 + tx * 4];
        tile[row][tx * 4 + 0] = v.x;
        tile[row][tx * 4 + 1] = v.y;
        tile[row][tx * 4 + 2] = v.z;
        tile[row][tx * 4 + 3] = v.w;
    }
    __syncthreads();
    int wc = t & 7, wr0 = t >> 3;
    #pragma unroll
    for (int p = 0; p < 2; ++p) {
        int cc = wr0 + p * 32;
        u16 pk[8];
        #pragma unroll
        for (int i = 0; i < 8; ++i)
            pk[i] = f2bf(tile[wc * 8 + i][cc]);
        uint4 v;
        v.x = (u32)pk[0] | ((u32)pk[1] << 16);
        v.y = (u32)pk[2] | ((u32)pk[3] << 16);
        v.z = (u32)pk[4] | ((u32)pk[5] << 16);
        v.w = (u32)pk[6] | ((u32)pk[7] << 16);
        *(uint4*)&dst[(size_t)(c0 + cc) * R + r0 + wc * 8] = v;
    }
}

// ---------------- LN + gate softmax/argmax (wave per token) -----------------
__global__ __launch_bounds__(256) void ln_gate_kernel(
    const float* __restrict__ x, const float* __restrict__ ln_g, const float* __restrict__ ln_b,
    const float* __restrict__ gate_w, const float* __restrict__ gate_b,
    u16* __restrict__ hA, u16* __restrict__ hB,
    int* __restrict__ idxb, float* __restrict__ pbuf)
{
    int wave = threadIdx.x >> 6, lane = threadIdx.x & 63;
    int tok = blockIdx.x * 4 + wave;
    const float* xr = x + (size_t)tok * DD + lane * 8;
    float4 v0 = *(const float4*)xr;
    float4 v1 = *(const float4*)(xr + 4);
    float xs[8] = {v0.x, v0.y, v0.z, v0.w, v1.x, v1.y, v1.z, v1.w};
    float s = 0.f, ss = 0.f;
    #pragma unroll
    for (int i = 0; i < 8; ++i) { s += xs[i]; ss += xs[i] * xs[i]; }
    s = wave_sum(s); ss = wave_sum(ss);
    float mu = s * (1.0f / DD);
    float var = ss * (1.0f / DD) - mu * mu;
    float rstd = rsqrtf(var + 1e-5f);

    #pragma unroll
    for (int br = 0; br < NBR; ++br) {
        u16* hb = br ? hB : hA;
        float part[8] = {0, 0, 0, 0, 0, 0, 0, 0};
        u16 hu[8];
        #pragma unroll
        for (int i = 0; i < 8; ++i) {
            int d = lane * 8 + i;
            float g = ln_g[br * DD + d], b = ln_b[br * DD + d];
            float h = (xs[i] - mu) * rstd * g + b;
            hu[i] = f2bf(h);
            const float* gw = gate_w + ((size_t)br * DD + d) * EE;
            float4 g0 = *(const float4*)gw;
            float4 g1 = *(const float4*)(gw + 4);
            part[0] += h * g0.x; part[1] += h * g0.y; part[2] += h * g0.z; part[3] += h * g0.w;
            part[4] += h * g1.x; part[5] += h * g1.y; part[6] += h * g1.z; part[7] += h * g1.w;
        }
        uint4 pk;
        pk.x = (u32)hu[0] | ((u32)hu[1] << 16);
        pk.y = (u32)hu[2] | ((u32)hu[3] << 16);
        pk.z = (u32)hu[4] | ((u32)hu[5] << 16);
        pk.w = (u32)hu[6] | ((u32)hu[7] << 16);
        *(uint4*)(hb + (size_t)tok * DD + lane * 8) = pk;

        float logit[8];
        #pragma unroll
        for (int e = 0; e < 8; ++e)
            logit[e] = wave_sum(part[e]) + gate_b[br * EE + e];
        float m = logit[0]; int bi = 0;
        #pragma unroll
        for (int e = 1; e < 8; ++e)
            if (logit[e] > m) { m = logit[e]; bi = e; }
        float sum = 0.f;
        #pragma unroll
        for (int e = 0; e < 8; ++e) sum += __expf(logit[e] - m);
        if (lane == 0) {
            idxb[br * NTOK + tok] = bi;
            pbuf[br * NTOK + tok] = 1.0f / sum;
        }
    }
}

// ---------------- routing: LDS histogram, 16 global atomics per block -------
__global__ __launch_bounds__(256) void route_kernel(
    const int* __restrict__ idxb, int* __restrict__ cnt, int* __restrict__ list)
{
    __shared__ int lcnt[GE];
    __shared__ int gbase[GE];
    int tid = threadIdx.x;
    int t = blockIdx.x * 256 + tid;
    if (tid < GE) lcnt[tid] = 0;
    __syncthreads();
    int e0 = idxb[t];
    int e1 = EE + idxb[NTOK + t];
    int r0 = atomicAdd(&lcnt[e0], 1);
    int r1 = atomicAdd(&lcnt[e1], 1);
    __syncthreads();
    if (tid < GE) {
        int c = lcnt[tid];
        gbase[tid] = c ? atomicAdd(&cnt[tid], c) : 0;
    }
    __syncthreads();
    list[(size_t)e0 * NTOK + gbase[e0] + r0] = t;
    list[(size_t)e1 * NTOK + gbase[e1] + r1] = t;
}

// ---------------- tile table (128-row granular) -----------------------------
__global__ void tilestart_kernel(const int* __restrict__ cnt, int* __restrict__ meta)
{
    int lane = threadIdx.x;   // 64 threads
    if (lane < 16) {
        int pbv = 0;
        for (int k = 0; k < lane; ++k) pbv += cnt[k];
        meta[lane] = pbv;
    }
    if (lane == 16) {
        int n = 0;
        for (int k = 0; k < 16; ++k) n += (cnt[k] + 127) >> 7;
        meta[33] = n;
    }
    for (int j = lane; j < MT128; j += 64) {
        int ge = -1, start = 0, tt = 0;
        #pragma unroll
        for (int k = 0; k < 16; ++k) {
            int mt = (cnt[k] + 127) >> 7;
            if (ge < 0) {
                if (j < start + mt) { ge = k; tt = j - start; }
                else start += mt;
            }
        }
        if (ge >= 0) meta[64 + j] = (ge << 20) | tt;
    }
}

// ---------------- 128x128 MFMA GEMM, BK=32, DOUBLE-buffer, counted vmcnt ----
// MODE 0: u[pos] = gelu(h[tok] @ W1[ge] + b1[ge])      A gathered via list
// MODE 1: moe{plane}[tok] = p * (u[pos] @ W2[ge] + b2) A dense, bf16 out
// MODE 2: dout = xres + A @ owt + out_b                A dense, f32 out
// grid: (ntile, tileidx) — ntile fastest for A-tile L2 reuse
// Per step: stage t+1 -> buf^1, s_waitcnt vmcnt(4) (counted, never 0 mid-loop),
// s_barrier, ds_read+MFMA from buf, s_barrier. Loads get a full step of cover.
template<int MODE>
__global__ __launch_bounds__(256, 3) void gemm_tile(
    const u16* __restrict__ A0, const u16* __restrict__ A1,
    const u16* __restrict__ Bt,
    const int* __restrict__ meta, const int* __restrict__ cnt,
    const int* __restrict__ list, const float* __restrict__ pbuf,
    const float* __restrict__ bias,
    u16* __restrict__ uout, u16* __restrict__ moeout,
    const float* __restrict__ xres, float* __restrict__ dout)
{
    constexpr int K = (MODE == 1) ? FF : DD;
    constexpr int N = (MODE == 0) ? FF : DD;
    constexpr int NSTEP = K / 32;

    __shared__ __align__(16) u16 As[2][128 * 32];
    __shared__ __align__(16) u16 Bs[2][128 * 32];
    __shared__ int rowtok[128];
    __shared__ float rowp[128];

    int ntile = blockIdx.x;
    int ge = 0, rb = 0, cnt_e = 1 << 30, pb = 0;
    if constexpr (MODE != 2) {
        int j = blockIdx.y;
        if (j >= meta[33]) return;
        int ev = meta[64 + j];
        ge = ev >> 20;
        rb = (ev & 0xfffff) << 7;
        cnt_e = cnt[ge];
        pb = meta[ge];
    } else {
        rb = blockIdx.y * 128;
    }

    int tid = threadIdx.x, wave = tid >> 6, lane = tid & 63;
    int wm = wave >> 1, wn = wave & 1;
    int fr = lane & 15, fq = lane >> 4;
    int r0 = wave * 16 + (lane >> 2);
    int sc = (lane & 3) ^ ((lane >> 3) & 3);   // swizzled source chunk (bank fix)

    const u16* Abase;
    if constexpr (MODE == 0) Abase = (ge >= 8) ? A1 : A0;
    else                     Abase = A0;
    const u16* Bte = Bt + ((MODE == 2) ? (size_t)0 : (size_t)ge * FF * DD);

    const u16 *aSrc0, *aSrc1, *bSrc0, *bSrc1;
    if constexpr (MODE == 0) {
        int lb = ge * NTOK;
        int g0 = rb + r0, g1 = g0 + 64;
        int t0 = (g0 < cnt_e) ? list[lb + g0] : list[lb];
        int t1 = (g1 < cnt_e) ? list[lb + g1] : list[lb];
        aSrc0 = Abase + (size_t)t0 * K + sc * 8;
        aSrc1 = Abase + (size_t)t1 * K + sc * 8;
    } else {
        size_t base = (MODE == 1) ? (size_t)(pb + rb) : (size_t)rb;
        aSrc0 = Abase + (base + r0) * (size_t)K + sc * 8;
        aSrc1 = Abase + (base + r0 + 64) * (size_t)K + sc * 8;
    }
    {
        int nrow = ntile * 128 + r0;
        bSrc0 = Bte + (size_t)nrow * K + sc * 8;
        bSrc1 = Bte + (size_t)(nrow + 64) * K + sc * 8;
    }

    if constexpr (MODE == 1) {
        if (tid < 128) {
            int g = rb + tid;
            int tk = (g < cnt_e) ? list[ge * NTOK + g] : -1;
            rowtok[tid] = tk;
            rowp[tid] = (tk >= 0) ? pbuf[(ge >> 3) * NTOK + tk] : 0.f;
        }
        ASM_LGKM0;
    }

    f32v4 acc[4][4];
    #pragma unroll
    for (int mi = 0; mi < 4; ++mi)
        #pragma unroll
        for (int ni = 0; ni < 4; ++ni)
            acc[mi][ni] = (f32v4){0.f, 0.f, 0.f, 0.f};

    int ch = fq ^ ((fr >> 1) & 3);             // swizzled read chunk (bank fix)

    // ---- prologue: stage step 0 into buf 0 ----
    gload16(aSrc0, &As[0][wave * 512]);
    gload16(aSrc1, &As[0][2048 + wave * 512]);
    gload16(bSrc0, &Bs[0][wave * 512]);
    gload16(bSrc1, &Bs[0][2048 + wave * 512]);
    aSrc0 += 32; aSrc1 += 32; bSrc0 += 32; bSrc1 += 32;

    #pragma unroll 2
    for (int t = 0; t < NSTEP; ++t) {
        const int cur = t & 1;
        if (t + 1 < NSTEP) {
            gload16(aSrc0, &As[cur ^ 1][wave * 512]);
            gload16(aSrc1, &As[cur ^ 1][2048 + wave * 512]);
            gload16(bSrc0, &Bs[cur ^ 1][wave * 512]);
            gload16(bSrc1, &Bs[cur ^ 1][2048 + wave * 512]);
            aSrc0 += 32; aSrc1 += 32; bSrc0 += 32; bSrc1 += 32;
            ASM_VMCNT4;    // step t's 4 loads landed; step t+1's 4 in flight
        } else {
            ASM_VMCNT0;
        }
        bar();

        bf16v8 af[4], bfr[4];
        #pragma unroll
        for (int mi = 0; mi < 4; ++mi)
            af[mi] = *(const bf16v8*)&As[cur][(wm * 64 + mi * 16 + fr) * 32 + ch * 8];
        #pragma unroll
        for (int ni = 0; ni < 4; ++ni)
            bfr[ni] = *(const bf16v8*)&Bs[cur][(wn * 64 + ni * 16 + fr) * 32 + ch * 8];
        #pragma unroll
        for (int mi = 0; mi < 4; ++mi)
            #pragma unroll
            for (int ni = 0; ni < 4; ++ni)
                acc[mi][ni] = __builtin_amdgcn_mfma_f32_16x16x32_bf16(
                    af[mi], bfr[ni], acc[mi][ni], 0, 0, 0);
        bar();
    }

    // ---- epilogue (C/D frag: col = lane&15, row = fq*4 + reg) ----
    #pragma unroll
    for (int mi = 0; mi < 4; ++mi) {
        #pragma unroll
        for (int ni = 0; ni < 4; ++ni) {
            int col = ntile * 128 + wn * 64 + ni * 16 + fr;
            float bn = (MODE == 2) ? bias[col] : bias[(size_t)ge * N + col];
            #pragma unroll
            for (int r = 0; r < 4; ++r) {
                int rr = wm * 64 + mi * 16 + fq * 4 + r;
                float v = acc[mi][ni][r] + bn;
                if constexpr (MODE == 0) {
                    if (rb + rr < cnt_e)
                        uout[(size_t)(pb + rb + rr) * FF + col] = f2bf(gelu_tanh(v));
                } else if constexpr (MODE == 1) {
                    int tok = rowtok[rr];
                    if (tok >= 0)
                        moeout[((size_t)(ge >> 3) * NTOK + tok) * DD + col] =
                            f2bf(v * rowp[rr]);
                } else {
                    size_t o = (size_t)(rb + rr) * DD + col;
                    dout[o] = xres[o] + v;
                }
            }
        }
    }
}

// ---------------- stylize: LN((moe0+moe1)/2)*(1+scale)+shift -> silu -> bf16
__global__ __launch_bounds__(256) void stylize_kernel(
    const u16* __restrict__ moe, const float* __restrict__ eo,
    const float* __restrict__ sn_g, const float* __restrict__ sn_b,
    u16* __restrict__ sbuf)
{
    int wave = threadIdx.x >> 6, lane = threadIdx.x & 63;
    int tok = blockIdx.x * 4 + wave;
    int b = tok / TT;
    const u16* mr = moe + (size_t)tok * DD + lane * 8;
    const u16* mr2 = mr + (size_t)NTOK * DD;
    uint4 pa = *(const uint4*)mr;
    uint4 pb = *(const uint4*)mr2;
    float os[8];
    os[0] = (bf2f(pa.x & 0xffff) + bf2f(pb.x & 0xffff)) * 0.5f;
    os[1] = (bf2f(pa.x >> 16)    + bf2f(pb.x >> 16))    * 0.5f;
    os[2] = (bf2f(pa.y & 0xffff) + bf2f(pb.y & 0xffff)) * 0.5f;
    os[3] = (bf2f(pa.y >> 16)    + bf2f(pb.y >> 16))    * 0.5f;
    os[4] = (bf2f(pa.z & 0xffff) + bf2f(pb.z & 0xffff)) * 0.5f;
    os[5] = (bf2f(pa.z >> 16)    + bf2f(pb.z >> 16))    * 0.5f;
    os[6] = (bf2f(pa.w & 0xffff) + bf2f(pb.w & 0xffff)) * 0.5f;
    os[7] = (bf2f(pa.w >> 16)    + bf2f(pb.w >> 16))    * 0.5f;
    float s = 0.f, ss = 0.f;
    #pragma unroll
    for (int i = 0; i < 8; ++i) { s += os[i]; ss += os[i] * os[i]; }
    s = wave_sum(s); ss = wave_sum(ss);
    float mu = s * (1.0f / DD);
    float var = ss * (1.0f / DD) - mu * mu;
    float rstd = rsqrtf(var + 1e-5f);
    u16 hu[8];
    #pragma unroll
    for (int i = 0; i < 8; ++i) {
        int d = lane * 8 + i;
        float h = (os[i] - mu) * rstd * sn_g[d] + sn_b[d];
        float scv = eo[(size_t)b * 1024 + d];
        float shv = eo[(size_t)b * 1024 + DD + d];
        h = h * (1.0f + scv) + shv;
        hu[i] = f2bf(silu(h));
    }
    uint4 pk;
    pk.x = (u32)hu[0] | ((u32)hu[1] << 16);
    pk.y = (u32)hu[2] | ((u32)hu[3] << 16);
    pk.z = (u32)hu[4] | ((u32)hu[5] << 16);
    pk.w = (u32)hu[6] | ((u32)hu[7] << 16);
    *(uint4*)(sbuf + (size_t)tok * DD + lane * 8) = pk;
}

// ---------------- host ----------------
extern "C" void kernel_launch(void* const* d_in, const int* in_sizes, int n_in,
                              void* d_out, int out_size, void* d_ws, size_t ws_size,
                              hipStream_t stream)
{
    const float* x      = (const float*)d_in[0];
    const float* emb    = (const float*)d_in[1];
    const float* ln_g   = (const float*)d_in[2];
    const float* ln_b   = (const float*)d_in[3];
    const float* gate_w = (const float*)d_in[4];
    const float* gate_b = (const float*)d_in[5];
    const float* w1     = (const float*)d_in[6];
    const float* b1     = (const float*)d_in[7];
    const float* w2     = (const float*)d_in[8];
    const float* b2     = (const float*)d_in[9];
    const float* emb_w  = (const float*)d_in[10];
    const float* emb_b  = (const float*)d_in[11];
    const float* sn_g   = (const float*)d_in[12];
    const float* sn_b   = (const float*)d_in[13];
    const float* out_w  = (const float*)d_in[14];
    const float* out_b  = (const float*)d_in[15];
    (void)n_in; (void)in_sizes; (void)out_size; (void)ws_size;

    const size_t szW    = (size_t)GE * FF * DD * 2;             // 33.5 MB each
    const size_t szOwt  = (size_t)DD * DD * 2;
    const size_t szH    = (size_t)NTOK * DD * 2;                // 12.85 MB
    const size_t szEo   = (size_t)BB * 2 * DD * 4;
    const size_t szP    = (size_t)NBR * NTOK * 4;
    const size_t szCnt  = 256, szMeta = 4096;
    const size_t szList = (size_t)GE * NTOK * 4;
    const size_t szU    = ((size_t)2 * NTOK + 256) * FF * 2;    // 103 MB
    const size_t szM    = (size_t)2 * NTOK * DD * 2;            // 25.7 MB (bf16)

    auto align256 = [](size_t v) { return (v + 255) & ~(size_t)255; };
    char* w = (char*)d_ws;
    size_t off = 0;
    auto take = [&](size_t bytes) -> void* {
        void* p = w + off;
        off = align256(off + bytes);
        return p;
    };
    u16*   w1t  = (u16*)take(szW);
    u16*   w2t  = (u16*)take(szW);
    u16*   owt  = (u16*)take(szOwt);
    u16*   hA   = (u16*)take(szH);       // reused as sbuf
    u16*   hB   = (u16*)take(szH);
    float* eo   = (float*)take(szEo);
    float* pbuf = (float*)take(szP);
    int*   idxb = (int*)take(szP);
    int*   cnt  = (int*)take(szCnt);
    int*   meta = (int*)take(szMeta);
    int*   list = (int*)take(szList);
    u16*   ubuf = (u16*)take(szU);
    u16*   moe  = (u16*)take(szM);

    // 1. weight transposes + eo + cnt init (one dispatch)
    mtrans_eo_kernel<<<8320, 256, 0, stream>>>(w1, w1t, w2, w2t, out_w, owt,
                                               emb, emb_w, emb_b, eo, cnt);

    // 2. LN + gate
    ln_gate_kernel<<<NTOK / 4, 256, 0, stream>>>(x, ln_g, ln_b, gate_w, gate_b,
                                                 hA, hB, idxb, pbuf);

    // 3. routing (LDS histogram) + tile table
    route_kernel<<<NTOK / 256, 256, 0, stream>>>(idxb, cnt, list);
    tilestart_kernel<<<1, 64, 0, stream>>>(cnt, meta);

    // 4. expert FFN (flat tile queues, ntile-fastest)
    gemm_tile<0><<<dim3(FF / 128, MT128), 256, 0, stream>>>(
        hA, hB, w1t, meta, cnt, list, nullptr, b1, ubuf, nullptr, nullptr, nullptr);
    gemm_tile<1><<<dim3(DD / 128, MT128), 256, 0, stream>>>(
        ubuf, nullptr, w2t, meta, cnt, list, pbuf, b2, nullptr, moe, nullptr, nullptr);

    // 5. stylization + output projection + residual
    stylize_kernel<<<NTOK / 4, 256, 0, stream>>>(moe, eo, sn_g, sn_b, hA);
    gemm_tile<2><<<dim3(DD / 128, NTOK / 128), 256, 0, stream>>>(
        hA, nullptr, owt, nullptr, nullptr, nullptr, nullptr, out_b,
        nullptr, nullptr, x, (float*)d_out);
}